// Round 2
// baseline (351.754 us; speedup 1.0000x reference)
//
#include <hip/hip_runtime.h>
#include <cstdint>
#include <cstddef>

typedef unsigned short u16;
typedef __bf16 bf16x8 __attribute__((ext_vector_type(8)));
typedef __bf16 bf16x4 __attribute__((ext_vector_type(4)));
typedef float f32x4 __attribute__((ext_vector_type(4)));

#define DEVI __device__ __forceinline__

DEVI u16 f2bf(float f){
  union { float f; unsigned u; } v; v.f = f;
  unsigned r = v.u + 0x7fffu + ((v.u >> 16) & 1u);
  return (u16)(r >> 16);
}

#if defined(__has_builtin)
#if __has_builtin(__builtin_amdgcn_exp2f)
#define EXP2F(x) __builtin_amdgcn_exp2f(x)
#else
#define EXP2F(x) exp2f(x)
#endif
#else
#define EXP2F(x) exp2f(x)
#endif

#define MFMA16(a,b,c) __builtin_amdgcn_mfma_f32_16x16x32_bf16((a),(b),(c),0,0,0)

// ---------------------------------------------------------------------------
// Workspace layout (bytes)
//  Wt  : bf16 [4][512][512] (n-major) @ 0         (2097152)
//  Qb  : bf16 [32][2048][64]          @ 2097152   (8388608)  (pre-scaled log2e/8)
//  Kb  : bf16 [32][2048][64]          @ 10485760  (8388608)
//  Vb  : bf16 [32][2048][64]          @ 18874368  (8388608)
//  Vt  : bf16 [32][64][2048]          @ 27262976  (8388608)
//  CTX : bf16 [8192][512]             @ 35651584  (8388608)
//  total 44040192 bytes (~42 MB)
// ---------------------------------------------------------------------------

// Transpose 4 weight matrices f32 [k][n] -> bf16 [n][k] (K-major for MFMA B).
__global__ void k_prep_w(const float* __restrict__ w0, const float* __restrict__ w1,
                         const float* __restrict__ w2, const float* __restrict__ w3,
                         u16* __restrict__ wt){
  __shared__ u16 tile[64][72];
  int p = blockIdx.z;
  const float* W = (p==0)?w0:((p==1)?w1:((p==2)?w2:w3));
  int k0 = blockIdx.x*64, n0 = blockIdx.y*64;
  int t = threadIdx.x;
  int tr = t >> 4, tc = t & 15;
  #pragma unroll
  for (int pass=0; pass<4; pass++){
    int row = pass*16 + tr;                           // k_local
    float4 a = *(const float4*)(W + (size_t)(k0+row)*512 + n0 + tc*4);
    tile[row][tc*4+0] = f2bf(a.x);
    tile[row][tc*4+1] = f2bf(a.y);
    tile[row][tc*4+2] = f2bf(a.z);
    tile[row][tc*4+3] = f2bf(a.w);
  }
  __syncthreads();
  #pragma unroll
  for (int pass=0; pass<4; pass++){
    int n = pass*16 + tr;                             // n_local
    ushort4 o;
    o.x = tile[tc*4+0][n];
    o.y = tile[tc*4+1][n];
    o.z = tile[tc*4+2][n];
    o.w = tile[tc*4+3][n];
    *(ushort4*)(wt + (size_t)p*262144 + (size_t)(n0+n)*512 + k0 + tc*4) = o;
  }
}

// Load 8 consecutive f32 and convert to bf16x8 (compiler emits cvt_pk).
DEVI bf16x8 ld_cvt8(const float* __restrict__ p){
  float4 a = *(const float4*)p;
  float4 b = *(const float4*)(p+4);
  bf16x8 r;
  r[0]=(__bf16)a.x; r[1]=(__bf16)a.y; r[2]=(__bf16)a.z; r[3]=(__bf16)a.w;
  r[4]=(__bf16)b.x; r[5]=(__bf16)b.y; r[6]=(__bf16)b.z; r[7]=(__bf16)b.w;
  return r;
}

// QKV projection: out = (X @ W + bias) * osc, X read as f32 and converted
// in-register. Output layout [b][h][s][64] bf16. Grid (64, 4, 3), block 256.
__global__ __launch_bounds__(256)
void k_gemm_qkv(const float* __restrict__ xq, const float* __restrict__ xk,
                const float* __restrict__ xv, const u16* __restrict__ wt,
                const float* __restrict__ bq, const float* __restrict__ bk,
                const float* __restrict__ bv,
                u16* __restrict__ qb, u16* __restrict__ kb, u16* __restrict__ vb){
  int p = blockIdx.z;
  const float* A = (p==0)?xq:((p==1)?xk:xv);
  const u16* Bt = wt + (size_t)p*262144;
  const float* bias = (p==0)?bq:((p==1)?bk:bv);
  u16* outp = (p==0)?qb:((p==1)?kb:vb);
  // Q pre-scaled by log2e/8 so attention softmax runs in the exp2 domain.
  float osc = (p==0)? (0.125f*1.44269504088896340736f) : 1.0f;
  int l = threadIdx.x & 63, w = threadIdx.x >> 6;
  int lr = l & 15, lg = l >> 4;
  int m0 = blockIdx.x*128 + (w>>1)*64;
  int n0 = blockIdx.y*128 + (w&1)*64;
  f32x4 acc[4][4] = {};
  for (int k0=0; k0<512; k0+=32){
    bf16x8 af[4], bfr[4];
    #pragma unroll
    for (int i=0;i<4;i++) af[i]  = ld_cvt8(A + (size_t)(m0+i*16+lr)*512 + k0 + lg*8);
    #pragma unroll
    for (int j=0;j<4;j++) bfr[j] = *(const bf16x8*)(Bt + (size_t)(n0+j*16+lr)*512 + k0 + lg*8);
    #pragma unroll
    for (int i=0;i<4;i++)
      #pragma unroll
      for (int j=0;j<4;j++)
        acc[i][j] = MFMA16(af[i], bfr[j], acc[i][j]);
  }
  #pragma unroll
  for (int i=0;i<4;i++){
    #pragma unroll
    for (int j=0;j<4;j++){
      int n = n0 + j*16 + lr;
      int h = n >> 6, d = n & 63;
      float bb = bias[n];
      #pragma unroll
      for (int rg=0;rg<4;rg++){
        int m = m0 + i*16 + 4*lg + rg;
        int b = m >> 11, s = m & 2047;
        float val = (acc[i][j][rg] + bb)*osc;
        __bf16 hb = (__bf16)val;
        outp[(((size_t)b*8 + h)*2048 + s)*64 + d] = *(u16*)&hb;
      }
    }
  }
}

// Transpose V: [bh][2048][64] -> [bh][64][2048] so PV B-operand is kv-contiguous.
__global__ void k_vt(const u16* __restrict__ vb, u16* __restrict__ vt){
  __shared__ u16 tile[64][72];
  int bh = blockIdx.z;
  int s0 = blockIdx.x*64;
  int t = threadIdx.x;
  int tr = t>>4, tc = t&15;
  const u16* src = vb + ((size_t)bh*2048 + s0)*64;
  #pragma unroll
  for (int pass=0; pass<4; pass++){
    int row = pass*16 + tr;                           // s_local
    ushort4 a = *(const ushort4*)(src + (size_t)row*64 + tc*4);
    tile[row][tc*4+0]=a.x; tile[row][tc*4+1]=a.y;
    tile[row][tc*4+2]=a.z; tile[row][tc*4+3]=a.w;
  }
  __syncthreads();
  u16* dst = vt + (size_t)bh*64*2048;
  #pragma unroll
  for (int pass=0; pass<4; pass++){
    int d = pass*16 + tr;
    ushort4 o;
    o.x = tile[tc*4+0][d]; o.y = tile[tc*4+1][d];
    o.z = tile[tc*4+2][d]; o.w = tile[tc*4+3][d];
    *(ushort4*)(dst + (size_t)d*2048 + s0 + tc*4) = o;
  }
}

// Flash attention. Grid (32,1,32), block 256 (4 waves x 16 q-rows each).
// Swapped QK^T (mfma(K,Q) -> S^T): softmax row-reduce is register-local +
// shfl_xor(16,32). Q comes pre-scaled by log2e/8 so exp is plain exp2.
// P reshaped via 2KB/wave XOR-swizzled LDS; rescale factors via __shfl.
__global__ __launch_bounds__(256)
void k_attn(const u16* __restrict__ qbuf, const u16* __restrict__ kbuf,
            const u16* __restrict__ vtb, u16* __restrict__ ctx){
  int l = threadIdx.x & 63, w = threadIdx.x >> 6;
  int lr = l & 15, lg = l >> 4;
  int bh = blockIdx.z; int b = bh >> 3, h = bh & 7;
  int q0 = blockIdx.x*64 + w*16;

  const u16* Qp = qbuf + ((size_t)bh*2048 + q0)*64;
  const u16* Kp = kbuf + (size_t)bh*2048*64;
  const u16* Vp = vtb  + (size_t)bh*64*2048;

  __shared__ __align__(16) u16 P_lds[4*1024];     // 4 waves x 16x64 bf16 (2KB each)
  u16* Pw = &P_lds[w*1024];

  bf16x8 qf[2];
  #pragma unroll
  for (int kk=0;kk<2;kk++)
    qf[kk] = *(const bf16x8*)(Qp + (size_t)lr*64 + kk*32 + lg*8);

  f32x4 oacc[4] = {};
  float m_run = -1e30f;
  float l_run = 0.f;

  for (int kv0 = 0; kv0 < 2048; kv0 += 64){
    // --- S^T = K * Q^T  (rows = kv, cols = q), already in log2 units ---
    f32x4 sacc[4] = {};
    #pragma unroll
    for (int kk=0;kk<2;kk++){
      bf16x8 kf[4];
      #pragma unroll
      for (int i=0;i<4;i++)
        kf[i] = *(const bf16x8*)(Kp + (size_t)(kv0 + i*16 + lr)*64 + kk*32 + lg*8);
      #pragma unroll
      for (int i=0;i<4;i++)
        sacc[i] = MFMA16(kf[i], qf[kk], sacc[i]);
    }
    // --- online softmax for q-row lr (16 S values per lane) ---
    float pm = -1e30f;
    #pragma unroll
    for (int i=0;i<4;i++){
      float m01 = fmaxf(sacc[i][0], sacc[i][1]);
      float m23 = fmaxf(sacc[i][2], sacc[i][3]);
      pm = fmaxf(pm, fmaxf(m01, m23));
    }
    pm = fmaxf(pm, __shfl_xor(pm, 16));
    pm = fmaxf(pm, __shfl_xor(pm, 32));
    float mn = fmaxf(m_run, pm);
    float fr = EXP2F(m_run - mn);
    // WAR guard: previous tile's P reads must complete before rewrite.
    asm volatile("s_waitcnt lgkmcnt(0)" ::: "memory");
    float psum = 0.f;
    #pragma unroll
    for (int i=0;i<4;i++){
      bf16x4 pk;
      #pragma unroll
      for (int rg=0;rg<4;rg++){
        float pv = EXP2F(sacc[i][rg] - mn);
        psum += pv;
        pk[rg] = (__bf16)pv;
      }
      int slot = (2*i + (lg>>1)) ^ (lr & 7);
      *(bf16x4*)((char*)Pw + lr*128 + (slot<<4) + (lg&1)*8) = pk;
    }
    psum += __shfl_xor(psum, 16);
    psum += __shfl_xor(psum, 32);
    l_run = l_run*fr + psum;
    m_run = mn;
    // --- rescale O: factor for accumulator row (4*lg+rg) via shfl ---
    #pragma unroll
    for (int rg=0;rg<4;rg++){
      float fv = __shfl(fr, 4*lg + rg);
      #pragma unroll
      for (int fj=0;fj<4;fj++)
        oacc[fj][rg] *= fv;
    }
    // --- O += P * V ---
    #pragma unroll
    for (int kk=0;kk<2;kk++){
      int slot = (4*kk + lg) ^ (lr & 7);
      bf16x8 pf = *(const bf16x8*)((char*)Pw + lr*128 + (slot<<4));
      bf16x8 vf[4];
      #pragma unroll
      for (int fj=0;fj<4;fj++)
        vf[fj] = *(const bf16x8*)(Vp + (size_t)(fj*16+lr)*2048 + kv0 + kk*32 + lg*8);
      #pragma unroll
      for (int fj=0;fj<4;fj++)
        oacc[fj] = MFMA16(pf, vf[fj], oacc[fj]);
    }
  }
  // --- finalize: O /= l_run, store to CTX [m][512] bf16 ---
  float inv = 1.f / l_run;
  #pragma unroll
  for (int rg=0;rg<4;rg++){
    float fv = __shfl(inv, 4*lg + rg);
    int qg = q0 + 4*lg + rg;
    #pragma unroll
    for (int fj=0;fj<4;fj++){
      int col = h*64 + fj*16 + lr;
      __bf16 hb = (__bf16)(oacc[fj][rg]*fv);
      ctx[((size_t)(b*2048 + qg))*512 + col] = *(u16*)&hb;
    }
  }
}

// Output projection + bias + residual + LayerNorm, fused.
// BM=16 rows/block, 8 waves each own a 64-col strip. Grid 512, block 512.
__global__ __launch_bounds__(512)
void k_outln(const u16* __restrict__ ctx, const u16* __restrict__ wto,
             const float* __restrict__ bo, const float* __restrict__ resid,
             const float* __restrict__ g, const float* __restrict__ beta,
             float* __restrict__ out){
  int l = threadIdx.x & 63, w = threadIdx.x >> 6;
  int lr = l & 15, lg = l >> 4;
  int m0 = blockIdx.x * 16;
  int nc0 = w * 64;
  f32x4 acc[4] = {};
  for (int k0=0;k0<512;k0+=32){
    bf16x8 af = *(const bf16x8*)(ctx + (size_t)(m0+lr)*512 + k0 + lg*8);
    bf16x8 bfr[4];
    #pragma unroll
    for (int j=0;j<4;j++) bfr[j] = *(const bf16x8*)(wto + (size_t)(nc0+j*16+lr)*512 + k0 + lg*8);
    #pragma unroll
    for (int j=0;j<4;j++)
      acc[j] = MFMA16(af, bfr[j], acc[j]);
  }
  float s1[4] = {}, s2[4] = {};
  #pragma unroll
  for (int j=0;j<4;j++){
    int col = nc0 + j*16 + lr;
    float bb = bo[col];
    #pragma unroll
    for (int rg=0;rg<4;rg++){
      int m = m0 + 4*lg + rg;
      float v = acc[j][rg] + bb + resid[(size_t)m*512 + col];
      acc[j][rg] = v;
      s1[rg] += v;
      s2[rg] += v*v;
    }
  }
  #pragma unroll
  for (int rg=0;rg<4;rg++){
    #pragma unroll
    for (int mk=1; mk<16; mk<<=1){
      s1[rg] += __shfl_xor(s1[rg], mk);
      s2[rg] += __shfl_xor(s2[rg], mk);
    }
  }
  __shared__ float red1[16][8], red2[16][8];
  if (lr == 0){
    #pragma unroll
    for (int rg=0;rg<4;rg++){
      int row = 4*lg + rg;
      red1[row][w] = s1[rg];
      red2[row][w] = s2[rg];
    }
  }
  __syncthreads();
  #pragma unroll
  for (int rg=0;rg<4;rg++){
    int row = 4*lg + rg;
    float t1 = 0.f, t2 = 0.f;
    #pragma unroll
    for (int ww=0; ww<8; ww++){ t1 += red1[row][ww]; t2 += red2[row][ww]; }
    float mu   = t1 * (1.f/512.f);
    float var  = t2 * (1.f/512.f) - mu*mu;
    float rstd = rsqrtf(var + 1e-5f);
    int m = m0 + row;
    #pragma unroll
    for (int j=0;j<4;j++){
      int col = nc0 + j*16 + lr;
      out[(size_t)m*512 + col] = (acc[j][rg] - mu)*rstd*g[col] + beta[col];
    }
  }
}

extern "C" void kernel_launch(void* const* d_in, const int* in_sizes, int n_in,
                              void* d_out, int out_size, void* d_ws, size_t ws_size,
                              hipStream_t stream){
  const float* q   = (const float*)d_in[0];
  const float* k   = (const float*)d_in[1];
  const float* v   = (const float*)d_in[2];
  const float* wq  = (const float*)d_in[3];
  const float* bq  = (const float*)d_in[4];
  const float* wk  = (const float*)d_in[5];
  const float* bk  = (const float*)d_in[6];
  const float* wv  = (const float*)d_in[7];
  const float* bv  = (const float*)d_in[8];
  const float* wo  = (const float*)d_in[9];
  const float* bo  = (const float*)d_in[10];
  const float* lng = (const float*)d_in[11];
  const float* lnb = (const float*)d_in[12];
  float* out = (float*)d_out;
  char* ws = (char*)d_ws;
  u16* wt  = (u16*)(ws + 0);
  u16* qb  = (u16*)(ws + 2097152);
  u16* kb  = (u16*)(ws + 10485760);
  u16* vb  = (u16*)(ws + 18874368);
  u16* vt  = (u16*)(ws + 27262976);
  u16* ctx = (u16*)(ws + 35651584);

  k_prep_w<<<dim3(8,8,4), 256, 0, stream>>>(wq, wk, wv, wo, wt);
  k_gemm_qkv<<<dim3(64,4,3), 256, 0, stream>>>(q, k, v, wt, bq, bk, bv, qb, kb, vb);
  k_vt<<<dim3(32,1,32), 256, 0, stream>>>(vb, vt);
  k_attn<<<dim3(32,1,32), 256, 0, stream>>>(qb, kb, vt, ctx);
  k_outln<<<512, 512, 0, stream>>>(ctx, wt + 3*262144, bo, q, lng, lnb, out);
}

// Round 3
// 243.867 us; speedup vs baseline: 1.4424x; 1.4424x over previous
//
#include <hip/hip_runtime.h>
#include <cstdint>
#include <cstddef>

typedef unsigned short u16;
typedef __bf16 bf16x8 __attribute__((ext_vector_type(8)));
typedef __bf16 bf16x4 __attribute__((ext_vector_type(4)));
typedef float f32x4 __attribute__((ext_vector_type(4)));

#define DEVI __device__ __forceinline__

DEVI u16 f2bf(float f){
  union { float f; unsigned u; } v; v.f = f;
  unsigned r = v.u + 0x7fffu + ((v.u >> 16) & 1u);
  return (u16)(r >> 16);
}

#if defined(__has_builtin)
#if __has_builtin(__builtin_amdgcn_exp2f)
#define EXP2F(x) __builtin_amdgcn_exp2f(x)
#else
#define EXP2F(x) exp2f(x)
#endif
#else
#define EXP2F(x) exp2f(x)
#endif

#define MFMA16(a,b,c) __builtin_amdgcn_mfma_f32_16x16x32_bf16((a),(b),(c),0,0,0)

// ---------------------------------------------------------------------------
// Workspace layout (bytes)
//  Wt    : bf16 [4][512][512] (n-major)  @ 0         (2097152)
//  Qb    : bf16 [32][2048][64]           @ 2097152   (8388608)  (pre-scaled log2e/8)
//  Kb    : bf16 [32][2048][64]           @ 10485760  (8388608)
//  Vt    : bf16 [32][64][2048]           @ 18874368  (8388608)
//  CTX   : bf16 [8192][512]              @ 27262976  (8388608)
//  Opart : bf16 [2][8192][512]           @ 35651584  (16777216)
//  Lpart : f32  [2][32][2048]            @ 52428800  (524288)
//  total 52953088 (~50.5 MB)
// ---------------------------------------------------------------------------

// Transpose 4 weight matrices f32 [k][n] -> bf16 [n][k] (K-major for MFMA B).
__global__ void k_prep_w(const float* __restrict__ w0, const float* __restrict__ w1,
                         const float* __restrict__ w2, const float* __restrict__ w3,
                         u16* __restrict__ wt){
  __shared__ u16 tile[64][72];
  int p = blockIdx.z;
  const float* W = (p==0)?w0:((p==1)?w1:((p==2)?w2:w3));
  int k0 = blockIdx.x*64, n0 = blockIdx.y*64;
  int t = threadIdx.x;
  int tr = t >> 4, tc = t & 15;
  #pragma unroll
  for (int pass=0; pass<4; pass++){
    int row = pass*16 + tr;                           // k_local
    float4 a = *(const float4*)(W + (size_t)(k0+row)*512 + n0 + tc*4);
    tile[row][tc*4+0] = f2bf(a.x);
    tile[row][tc*4+1] = f2bf(a.y);
    tile[row][tc*4+2] = f2bf(a.z);
    tile[row][tc*4+3] = f2bf(a.w);
  }
  __syncthreads();
  #pragma unroll
  for (int pass=0; pass<4; pass++){
    int n = pass*16 + tr;                             // n_local
    ushort4 o;
    o.x = tile[tc*4+0][n];
    o.y = tile[tc*4+1][n];
    o.z = tile[tc*4+2][n];
    o.w = tile[tc*4+3][n];
    *(ushort4*)(wt + (size_t)p*262144 + (size_t)(n0+n)*512 + k0 + tc*4) = o;
  }
}

// Load 8 consecutive f32 and convert to bf16x8 (compiler emits cvt_pk).
DEVI bf16x8 ld_cvt8(const float* __restrict__ p){
  float4 a = *(const float4*)p;
  float4 b = *(const float4*)(p+4);
  bf16x8 r;
  r[0]=(__bf16)a.x; r[1]=(__bf16)a.y; r[2]=(__bf16)a.z; r[3]=(__bf16)a.w;
  r[4]=(__bf16)b.x; r[5]=(__bf16)b.y; r[6]=(__bf16)b.z; r[7]=(__bf16)b.w;
  return r;
}

// QKV projection: out = (X @ W + bias) * osc, X read as f32, converted
// in-register. Q,K -> [b][h][s][64]; V -> transposed [b][h][64][s].
// Grid (64, 4, 3), block 256.
__global__ __launch_bounds__(256)
void k_gemm_qkv(const float* __restrict__ xq, const float* __restrict__ xk,
                const float* __restrict__ xv, const u16* __restrict__ wt,
                const float* __restrict__ bq, const float* __restrict__ bk,
                const float* __restrict__ bv,
                u16* __restrict__ qb, u16* __restrict__ kb, u16* __restrict__ vt){
  int p = blockIdx.z;
  const float* A = (p==0)?xq:((p==1)?xk:xv);
  const u16* Bt = wt + (size_t)p*262144;
  const float* bias = (p==0)?bq:((p==1)?bk:bv);
  // Q pre-scaled by log2e/8 so attention softmax runs in the exp2 domain.
  float osc = (p==0)? (0.125f*1.44269504088896340736f) : 1.0f;
  int l = threadIdx.x & 63, w = threadIdx.x >> 6;
  int lr = l & 15, lg = l >> 4;
  int m0 = blockIdx.x*128 + (w>>1)*64;
  int n0 = blockIdx.y*128 + (w&1)*64;
  f32x4 acc[4][4] = {};
  for (int k0=0; k0<512; k0+=32){
    bf16x8 af[4], bfr[4];
    #pragma unroll
    for (int i=0;i<4;i++) af[i]  = ld_cvt8(A + (size_t)(m0+i*16+lr)*512 + k0 + lg*8);
    #pragma unroll
    for (int j=0;j<4;j++) bfr[j] = *(const bf16x8*)(Bt + (size_t)(n0+j*16+lr)*512 + k0 + lg*8);
    #pragma unroll
    for (int i=0;i<4;i++)
      #pragma unroll
      for (int j=0;j<4;j++)
        acc[i][j] = MFMA16(af[i], bfr[j], acc[i][j]);
  }
  if (p < 2){
    u16* outp = (p==0)?qb:kb;
    #pragma unroll
    for (int i=0;i<4;i++){
      #pragma unroll
      for (int j=0;j<4;j++){
        int n = n0 + j*16 + lr;
        int h = n >> 6, d = n & 63;
        float bb = bias[n];
        #pragma unroll
        for (int rg=0;rg<4;rg++){
          int m = m0 + i*16 + 4*lg + rg;
          int b = m >> 11, s = m & 2047;
          float val = (acc[i][j][rg] + bb)*osc;
          __bf16 hb = (__bf16)val;
          outp[(((size_t)b*8 + h)*2048 + s)*64 + d] = *(u16*)&hb;
        }
      }
    }
  } else {
    // V: write transposed [bh][d][s]; 4 rg values are consecutive in s.
    #pragma unroll
    for (int i=0;i<4;i++){
      #pragma unroll
      for (int j=0;j<4;j++){
        int n = n0 + j*16 + lr;
        int h = n >> 6, d = n & 63;
        float bb = bias[n];
        int m = m0 + i*16 + 4*lg;
        int b = m >> 11, s = m & 2047;
        ushort4 o;
        #pragma unroll
        for (int rg=0;rg<4;rg++){
          __bf16 hb = (__bf16)(acc[i][j][rg] + bb);
          ((u16*)&o)[rg] = *(u16*)&hb;
        }
        *(ushort4*)(vt + (((size_t)(b*8+h)*64 + d)*2048 + s)) = o;
      }
    }
  }
}

// Flash attention, fixed-max softmax (exp2 domain, M=16), kv-split x2.
// Grid (16, 2, 32), block 256 (4 waves x 32 q-rows). No shuffles / no LDS
// broadcasts / no asm walls in the kv loop; P ping-pongs in per-wave LDS.
__global__ __launch_bounds__(256, 4)
void k_attn(const u16* __restrict__ qbuf, const u16* __restrict__ kbuf,
            const u16* __restrict__ vtb, u16* __restrict__ opart,
            float* __restrict__ lpart){
  int l = threadIdx.x & 63, w = threadIdx.x >> 6;
  int lr = l & 15, lg = l >> 4;
  int bh = blockIdx.z; int b = bh >> 3, h = bh & 7;
  int split = blockIdx.y;
  int q0 = blockIdx.x*128 + w*32;
  int kvbase = split*1024;

  const u16* Qp = qbuf + ((size_t)bh*2048 + q0)*64;
  const u16* Kp = kbuf + (size_t)bh*2048*64;
  const u16* Vp = vtb  + (size_t)bh*64*2048;

  __shared__ __align__(16) u16 P_lds[4*2*2048];   // 4 waves x ping-pong x 4KB
  u16* Pw = &P_lds[w*4096];

  bf16x8 qf[2][2];
  #pragma unroll
  for (int j=0;j<2;j++)
    #pragma unroll
    for (int kk=0;kk<2;kk++)
      qf[j][kk] = *(const bf16x8*)(Qp + (size_t)(j*16+lr)*64 + kk*32 + lg*8);

  f32x4 oacc[2][4] = {};
  float lsum[2] = {0.f, 0.f};
  const float M = 16.0f;                          // fixed max, log2 units

  for (int t = 0; t < 16; ++t){
    int kv0 = kvbase + t*64;
    u16* Pbuf = Pw + (t&1)*2048;
    // --- S^T = K * Q^T (rows = kv, cols = q), log2 units ---
    f32x4 sacc[4][2] = {};
    #pragma unroll
    for (int kk=0;kk<2;kk++){
      bf16x8 kf[4];
      #pragma unroll
      for (int i=0;i<4;i++)
        kf[i] = *(const bf16x8*)(Kp + (size_t)(kv0 + i*16 + lr)*64 + kk*32 + lg*8);
      #pragma unroll
      for (int i=0;i<4;i++)
        #pragma unroll
        for (int j=0;j<2;j++)
          sacc[i][j] = MFMA16(kf[i], qf[j][kk], sacc[i][j]);
    }
    // --- P = exp2(S - M); per-lane partial row-sums only ---
    #pragma unroll
    for (int j=0;j<2;j++){
      int qrow = lr + 16*j;
      #pragma unroll
      for (int i=0;i<4;i++){
        bf16x4 pk;
        #pragma unroll
        for (int rg=0;rg<4;rg++){
          float pv = EXP2F(sacc[i][j][rg] - M);
          lsum[j] += pv;
          pk[rg] = (__bf16)pv;
        }
        int o    = 8*lg + 32*i;                   // byte offset along kv
        int slot = (o >> 4) ^ (qrow & 7);
        *(bf16x4*)((char*)Pbuf + qrow*128 + (slot<<4) + (o & 15)) = pk;
      }
    }
    // --- O += P * V ---
    #pragma unroll
    for (int kk=0;kk<2;kk++){
      bf16x8 pf[2];
      #pragma unroll
      for (int fi=0;fi<2;fi++){
        int qrow = fi*16 + lr;
        int slot = (4*kk + lg) ^ (qrow & 7);
        pf[fi] = *(const bf16x8*)((char*)Pbuf + qrow*128 + (slot<<4));
      }
      bf16x8 vf[4];
      #pragma unroll
      for (int fj=0;fj<4;fj++)
        vf[fj] = *(const bf16x8*)(Vp + (size_t)(fj*16+lr)*2048 + kv0 + kk*32 + lg*8);
      #pragma unroll
      for (int fi=0;fi<2;fi++)
        #pragma unroll
        for (int fj=0;fj<4;fj++)
          oacc[fi][fj] = MFMA16(pf[fi], vf[fj], oacc[fi][fj]);
    }
  }
  // --- row-sum reduce (only now), store partial O (unnormalized) + l ---
  #pragma unroll
  for (int j=0;j<2;j++){
    lsum[j] += __shfl_xor(lsum[j], 16);
    lsum[j] += __shfl_xor(lsum[j], 32);
  }
  if (lg == 0){
    lpart[((size_t)split*32 + bh)*2048 + q0 + lr]      = lsum[0];
    lpart[((size_t)split*32 + bh)*2048 + q0 + 16 + lr] = lsum[1];
  }
  u16* op = opart + (size_t)split*8192*512;
  #pragma unroll
  for (int fi=0;fi<2;fi++){
    #pragma unroll
    for (int fj=0;fj<4;fj++){
      int col = h*64 + fj*16 + lr;
      #pragma unroll
      for (int rg=0;rg<4;rg++){
        int qg = q0 + fi*16 + 4*lg + rg;
        __bf16 hb = (__bf16)oacc[fi][fj][rg];
        op[((size_t)(b*2048 + qg))*512 + col] = *(u16*)&hb;
      }
    }
  }
}

// Combine the 2 kv-split partials: ctx = (O0+O1)/(l0+l1). Grid 2048 x 256.
__global__ void k_combine(const u16* __restrict__ opart,
                          const float* __restrict__ lpart,
                          u16* __restrict__ ctx){
  int t = blockIdx.x*256 + threadIdx.x;           // 524288 threads x 8 elems
  int m  = t >> 6;
  int c8 = (t & 63) * 8;
  int b = m >> 11, q = m & 2047;
  int h = c8 >> 6;
  int bh = b*8 + h;
  float l0 = lpart[(size_t)bh*2048 + q];
  float l1 = lpart[(size_t)(32 + bh)*2048 + q];
  float inv = 1.f / (l0 + l1);
  bf16x8 a0 = *(const bf16x8*)(opart + (size_t)m*512 + c8);
  bf16x8 a1 = *(const bf16x8*)(opart + (size_t)(8192 + m)*512 + c8);
  bf16x8 r;
  #pragma unroll
  for (int e=0;e<8;e++)
    r[e] = (__bf16)(((float)a0[e] + (float)a1[e]) * inv);
  *(bf16x8*)(ctx + (size_t)m*512 + c8) = r;
}

// Output projection + bias + residual + LayerNorm, fused.
// BM=16 rows/block, 8 waves each own a 64-col strip. Grid 512, block 512.
__global__ __launch_bounds__(512)
void k_outln(const u16* __restrict__ ctx, const u16* __restrict__ wto,
             const float* __restrict__ bo, const float* __restrict__ resid,
             const float* __restrict__ g, const float* __restrict__ beta,
             float* __restrict__ out){
  int l = threadIdx.x & 63, w = threadIdx.x >> 6;
  int lr = l & 15, lg = l >> 4;
  int m0 = blockIdx.x * 16;
  int nc0 = w * 64;
  f32x4 acc[4] = {};
  for (int k0=0;k0<512;k0+=32){
    bf16x8 af = *(const bf16x8*)(ctx + (size_t)(m0+lr)*512 + k0 + lg*8);
    bf16x8 bfr[4];
    #pragma unroll
    for (int j=0;j<4;j++) bfr[j] = *(const bf16x8*)(wto + (size_t)(nc0+j*16+lr)*512 + k0 + lg*8);
    #pragma unroll
    for (int j=0;j<4;j++)
      acc[j] = MFMA16(af, bfr[j], acc[j]);
  }
  float s1[4] = {}, s2[4] = {};
  #pragma unroll
  for (int j=0;j<4;j++){
    int col = nc0 + j*16 + lr;
    float bb = bo[col];
    #pragma unroll
    for (int rg=0;rg<4;rg++){
      int m = m0 + 4*lg + rg;
      float v = acc[j][rg] + bb + resid[(size_t)m*512 + col];
      acc[j][rg] = v;
      s1[rg] += v;
      s2[rg] += v*v;
    }
  }
  #pragma unroll
  for (int rg=0;rg<4;rg++){
    #pragma unroll
    for (int mk=1; mk<16; mk<<=1){
      s1[rg] += __shfl_xor(s1[rg], mk);
      s2[rg] += __shfl_xor(s2[rg], mk);
    }
  }
  __shared__ float red1[16][8], red2[16][8];
  if (lr == 0){
    #pragma unroll
    for (int rg=0;rg<4;rg++){
      int row = 4*lg + rg;
      red1[row][w] = s1[rg];
      red2[row][w] = s2[rg];
    }
  }
  __syncthreads();
  #pragma unroll
  for (int rg=0;rg<4;rg++){
    int row = 4*lg + rg;
    float t1 = 0.f, t2 = 0.f;
    #pragma unroll
    for (int ww=0; ww<8; ww++){ t1 += red1[row][ww]; t2 += red2[row][ww]; }
    float mu   = t1 * (1.f/512.f);
    float var  = t2 * (1.f/512.f) - mu*mu;
    float rstd = rsqrtf(var + 1e-5f);
    int m = m0 + row;
    #pragma unroll
    for (int j=0;j<4;j++){
      int col = nc0 + j*16 + lr;
      out[(size_t)m*512 + col] = (acc[j][rg] - mu)*rstd*g[col] + beta[col];
    }
  }
}

extern "C" void kernel_launch(void* const* d_in, const int* in_sizes, int n_in,
                              void* d_out, int out_size, void* d_ws, size_t ws_size,
                              hipStream_t stream){
  const float* q   = (const float*)d_in[0];
  const float* k   = (const float*)d_in[1];
  const float* v   = (const float*)d_in[2];
  const float* wq  = (const float*)d_in[3];
  const float* bq  = (const float*)d_in[4];
  const float* wk  = (const float*)d_in[5];
  const float* bk  = (const float*)d_in[6];
  const float* wv  = (const float*)d_in[7];
  const float* bv  = (const float*)d_in[8];
  const float* wo  = (const float*)d_in[9];
  const float* bo  = (const float*)d_in[10];
  const float* lng = (const float*)d_in[11];
  const float* lnb = (const float*)d_in[12];
  float* out = (float*)d_out;
  char* ws = (char*)d_ws;
  u16*   wt    = (u16*)(ws + 0);
  u16*   qb    = (u16*)(ws + 2097152);
  u16*   kb    = (u16*)(ws + 10485760);
  u16*   vt    = (u16*)(ws + 18874368);
  u16*   ctx   = (u16*)(ws + 27262976);
  u16*   opart = (u16*)(ws + 35651584);
  float* lpart = (float*)(ws + 52428800);

  k_prep_w<<<dim3(8,8,4), 256, 0, stream>>>(wq, wk, wv, wo, wt);
  k_gemm_qkv<<<dim3(64,4,3), 256, 0, stream>>>(q, k, v, wt, bq, bk, bv, qb, kb, vt);
  k_attn<<<dim3(16,2,32), 256, 0, stream>>>(qb, kb, vt, opart, lpart);
  k_combine<<<2048, 256, 0, stream>>>(opart, lpart, ctx);
  k_outln<<<512, 512, 0, stream>>>(ctx, wt + 3*262144, bo, q, lng, lnb, out);
}